// Round 2
// baseline (384.498 us; speedup 1.0000x reference)
//
#include <hip/hip_runtime.h>
#include <stdint.h>

typedef unsigned short u16;
typedef unsigned int u32;
typedef __attribute__((ext_vector_type(8))) short short8;
typedef __attribute__((ext_vector_type(4))) float floatx4;

#define BATCH   131072
#define NA      3
#define OBS     30
#define ACTD    9
#define HID     128
#define HEADS   4
#define HD      32
#define MB      16
#define ROWS    (MB*NA)     // 48
#define LDC     136         // padded row stride (2-way bank aliasing only, free)
#define LDOA    72          // oa input tile stride

// prepacked-weight offsets in d_ws, in u16 units (each fragment = 64 lanes x 8 bf16)
#define OFF_WO    0         // [3][nt=8][kt=1][64][8]
#define OFF_WOA   12288     // [3][8][2][64][8]
#define OFF_WQ    36864     // [8][4][64][8]
#define OFF_WK    53248
#define OFF_WV    69632
#define OFF_WC1   86016     // [3][8][8][64][8]
#define OFF_WC2   184320    // [3][1][4][64][8] (N padded 9->16)
#define PRE_TOTAL 190464    // u16 elements (~372 KB of d_ws)

__device__ __forceinline__ float bf2f(u16 h) {
    union { u32 u; float f; } v; v.u = ((u32)h) << 16; return v.f;
}
__device__ __forceinline__ u16 f2bf(float f) {
    union { float f; u32 u; } v; v.f = f;
    u32 r = v.u + 0x7fffu + ((v.u >> 16) & 1u);
    return (u16)(r >> 16);
}
__device__ __forceinline__ float leaky(float x) { return x >= 0.f ? x : 0.01f * x; }

// ------------- weight prepack: f32 [k][n] -> bf16 MFMA B-fragment order -------------
__global__ void prepack_kernel(const float* __restrict__ Wo,  const float* __restrict__ Woa,
                               const float* __restrict__ Wq,  const float* __restrict__ Wk,
                               const float* __restrict__ Wv,  const float* __restrict__ Wc1,
                               const float* __restrict__ Wc2, u16* __restrict__ out) {
    int i = blockIdx.x * blockDim.x + threadIdx.x;
    if (i >= PRE_TOTAL) return;
    const float* src; int K, KT, perA, base, Nsrc, Nlim;
    if (i < OFF_WOA)      { src = Wo;  K = 30;  KT = 1; perA = 4096;  base = OFF_WO;  Nsrc = 128; Nlim = 128; }
    else if (i < OFF_WQ)  { src = Woa; K = 39;  KT = 2; perA = 8192;  base = OFF_WOA; Nsrc = 128; Nlim = 128; }
    else if (i < OFF_WK)  { src = Wq;  K = 128; KT = 4; perA = 16384; base = OFF_WQ;  Nsrc = 128; Nlim = 128; }
    else if (i < OFF_WV)  { src = Wk;  K = 128; KT = 4; perA = 16384; base = OFF_WK;  Nsrc = 128; Nlim = 128; }
    else if (i < OFF_WC1) { src = Wv;  K = 128; KT = 4; perA = 16384; base = OFF_WV;  Nsrc = 128; Nlim = 128; }
    else if (i < OFF_WC2) { src = Wc1; K = 256; KT = 8; perA = 32768; base = OFF_WC1; Nsrc = 128; Nlim = 128; }
    else                  { src = Wc2; K = 128; KT = 4; perA = 2048;  base = OFF_WC2; Nsrc = 9;   Nlim = 9;   }
    int j = i - base;
    int agent = j / perA;
    int r = j - agent * perA;
    int e = r & 7, lane = (r >> 3) & 63, fk = r >> 9;   // fk = nt*KT + kt
    int kt = fk % KT, nt = fk / KT;
    int n = nt * 16 + (lane & 15);
    int k = kt * 32 + (lane >> 4) * 8 + e;
    u16 v = 0;
    if (k < K && n < Nlim) v = f2bf(src[(agent * K + k) * Nsrc + n]);
    out[i] = v;   // zero-padded K rows / N cols handled here
}

// ---------------- fused forward ----------------
__global__ __launch_bounds__(256) void fused_kernel(
    const float* __restrict__ obs, const float* __restrict__ act,
    const float* __restrict__ b_o, const float* __restrict__ b_oa,
    const float* __restrict__ bq,  const float* __restrict__ bk_, const float* __restrict__ bv,
    const float* __restrict__ bc1, const float* __restrict__ bc2,
    const u16* __restrict__ pre, float* __restrict__ out)
{
    __shared__ __align__(16) u16 s_mem[4 * ROWS * LDC];        // 52224 B
    __shared__ float s_probs[MB * HEADS * NA * NA];            // 2304 B
    u16* s_oemb  = s_mem;                    // o_emb (persistent)
    u16* s_oaemb = s_mem + ROWS * LDC;       // oa_emb -> attn_out
    u16* s_bufA  = s_mem + 2 * ROWS * LDC;   // oa-tile -> Q -> V
    u16* s_bufB  = s_mem + 3 * ROWS * LDC;   // K -> h

    const int tid  = threadIdx.x;
    const int wave = tid >> 6, lane = tid & 63;
    const int l15  = lane & 15, quad = lane >> 4;
    const int b0   = blockIdx.x * MB;
    const short8* preV = (const short8*)pre;

    // ---- stage 0: stage [obs|act|0] input tile (f32 -> bf16), layout [agent][MB][LDOA] ----
    for (int g = tid; g < MB * NA * OBS; g += 256) {
        int bl = g / (NA * OBS), r = g - bl * (NA * OBS), n = r / OBS, k = r - n * OBS;
        s_bufA[n * (MB * LDOA) + bl * LDOA + k] = f2bf(obs[((b0 + bl) * NA + n) * OBS + k]);
    }
    for (int g = tid; g < MB * NA * ACTD; g += 256) {
        int bl = g / (NA * ACTD), r = g - bl * (NA * ACTD), n = r / ACTD, k = r - n * ACTD;
        s_bufA[n * (MB * LDOA) + bl * LDOA + OBS + k] = f2bf(act[((b0 + bl) * NA + n) * ACTD + k]);
    }
    for (int g = tid; g < MB * NA * 25; g += 256) {   // zero k = 39..63
        int bl = g / (NA * 25), r = g - bl * (NA * 25), n = r / 25, k = r - n * 25;
        s_bufA[n * (MB * LDOA) + bl * LDOA + 39 + k] = 0;
    }
    __syncthreads();

    // ---- stage 1: per-agent embeds (o_emb K=32pad, oa_emb K=64pad) ----
    for (int sj = wave; sj < 12; sj += 4) {
        int osel = sj / 6;              // 0: o_emb  1: oa_emb
        int rem = sj % 6, agent = rem >> 1, nh = rem & 1;
        int KTn = osel ? 2 : 1;
        const float* bias = osel ? b_oa : b_o;
        int preBase = osel ? (OFF_WOA / 8 + agent * 1024) : (OFF_WO / 8 + agent * 512);
        floatx4 acc[4] = {};
        for (int kt = 0; kt < KTn; kt++) {
            short8 a = *(const short8*)&s_bufA[agent * (MB * LDOA) + l15 * LDOA + kt * 32 + quad * 8];
            for (int n4 = 0; n4 < 4; n4++) {
                int nt = nh * 4 + n4;
                short8 b = preV[preBase + (nt * KTn + kt) * 64 + lane];
                acc[n4] = __builtin_amdgcn_mfma_f32_16x16x32_bf16(a, b, acc[n4], 0, 0, 0);
            }
        }
        u16* dst = osel ? s_oaemb : s_oemb;
        for (int n4 = 0; n4 < 4; n4++) {
            int col = (nh * 4 + n4) * 16 + l15;
            float bb = bias[agent * HID + col];
            for (int rg = 0; rg < 4; rg++) {
                int m = quad * 4 + rg;   // D: row = quad*4+reg, col = lane&15
                dst[(m * NA + agent) * LDC + col] = f2bf(leaky(acc[n4][rg] + bb));
            }
        }
    }
    __syncthreads();

    // ---- stage 2: Q (from o_emb, pre-scaled 1/sqrt(32)) and K (from oa_emb) ----
    for (int sj = wave; sj < 12; sj += 4) {
        int proj = sj / 6;              // 0: Q  1: K
        int rem = sj % 6, mt = rem >> 1, nh = rem & 1;
        const u16* A = proj ? s_oaemb : s_oemb;
        int preBase = (proj ? OFF_WK : OFF_WQ) / 8;
        const float* bias = proj ? bk_ : bq;
        floatx4 acc[4] = {};
        for (int kt = 0; kt < 4; kt++) {
            short8 a = *(const short8*)&A[(mt * 16 + l15) * LDC + kt * 32 + quad * 8];
            for (int n4 = 0; n4 < 4; n4++) {
                int nt = nh * 4 + n4;
                short8 b = preV[preBase + (nt * 4 + kt) * 64 + lane];
                acc[n4] = __builtin_amdgcn_mfma_f32_16x16x32_bf16(a, b, acc[n4], 0, 0, 0);
            }
        }
        u16* dst = proj ? s_bufB : s_bufA;
        float scale = proj ? 1.0f : 0.17677669529663687f;   // 1/sqrt(HD) folded into Q
        for (int n4 = 0; n4 < 4; n4++) {
            int col = (nh * 4 + n4) * 16 + l15;
            float bb = bias[col];
            for (int rg = 0; rg < 4; rg++) {
                int m = mt * 16 + quad * 4 + rg;
                dst[m * LDC + col] = f2bf((acc[n4][rg] + bb) * scale);
            }
        }
    }
    __syncthreads();

    // ---- stage 3a: masked softmax probs, one thread per (elem, head, n) ----
    if (tid < MB * HEADS * NA) {
        int e = tid / (HEADS * NA), r = tid % (HEADS * NA), h = r / NA, n = r % NA;
        float q[32];
        const short8* qp = (const short8*)&s_bufA[(e * NA + n) * LDC + h * HD];
        for (int c = 0; c < 4; c++) { short8 v = qp[c]; for (int j = 0; j < 8; j++) q[c * 8 + j] = bf2f((u16)v[j]); }
        float sc[3];
        for (int m = 0; m < NA; m++) {
            const short8* kp = (const short8*)&s_bufB[(e * NA + m) * LDC + h * HD];
            float s = 0.f;
            for (int c = 0; c < 4; c++) { short8 v = kp[c]; for (int j = 0; j < 8; j++) s += q[c * 8 + j] * bf2f((u16)v[j]); }
            sc[m] = s;
        }
        sc[n] = -1e30f;                                   // diag mask
        float mx = fmaxf(fmaxf(sc[0], sc[1]), sc[2]);
        float p0 = __expf(sc[0] - mx), p1 = __expf(sc[1] - mx), p2 = __expf(sc[2] - mx);
        if (n == 0) p0 = 0.f; if (n == 1) p1 = 0.f; if (n == 2) p2 = 0.f;
        float inv = 1.f / (p0 + p1 + p2);
        float* pp = &s_probs[((e * HEADS + h) * NA + n) * NA];
        pp[0] = p0 * inv; pp[1] = p1 * inv; pp[2] = p2 * inv;
    }
    __syncthreads();

    // ---- stage 3b: V = oa_emb @ Wv + bv  (into s_bufA; Q is dead) ----
    for (int sj = wave; sj < 6; sj += 4) {
        int mt = sj >> 1, nh = sj & 1;
        floatx4 acc[4] = {};
        for (int kt = 0; kt < 4; kt++) {
            short8 a = *(const short8*)&s_oaemb[(mt * 16 + l15) * LDC + kt * 32 + quad * 8];
            for (int n4 = 0; n4 < 4; n4++) {
                int nt = nh * 4 + n4;
                short8 b = preV[OFF_WV / 8 + (nt * 4 + kt) * 64 + lane];
                acc[n4] = __builtin_amdgcn_mfma_f32_16x16x32_bf16(a, b, acc[n4], 0, 0, 0);
            }
        }
        for (int n4 = 0; n4 < 4; n4++) {
            int col = (nh * 4 + n4) * 16 + l15;
            float bb = bv[col];
            for (int rg = 0; rg < 4; rg++) {
                int m = mt * 16 + quad * 4 + rg;
                s_bufA[m * LDC + col] = f2bf(acc[n4][rg] + bb);
            }
        }
    }
    __syncthreads();

    // ---- stage 3c: attn_out = probs @ V  (into s_oaemb; oa_emb is dead) ----
    if (tid < MB * HEADS * NA) {
        int e = tid / (HEADS * NA), r = tid % (HEADS * NA), h = r / NA, n = r % NA;
        const float* pp = &s_probs[((e * HEADS + h) * NA + n) * NA];
        float o[32];
        for (int j = 0; j < 32; j++) o[j] = 0.f;
        for (int m = 0; m < NA; m++) {
            float p = pp[m];
            const short8* vp = (const short8*)&s_bufA[(e * NA + m) * LDC + h * HD];
            for (int c = 0; c < 4; c++) { short8 v = vp[c]; for (int j = 0; j < 8; j++) o[c * 8 + j] += p * bf2f((u16)v[j]); }
        }
        u16* dst = &s_oaemb[(e * NA + n) * LDC + h * HD];
        for (int c = 0; c < 4; c++) {
            short8 w;
            for (int j = 0; j < 8; j++) w[j] = (short)f2bf(o[c * 8 + j]);
            *(short8*)&dst[c * 8] = w;
        }
    }
    __syncthreads();

    // ---- stage 4: critic layer 1, K-split concat: kt<4 from o_emb, kt>=4 from attn ----
    for (int sj = wave; sj < 12; sj += 4) {
        int agent = sj >> 2, nq = sj & 3;
        floatx4 acc[2] = {};
        for (int kt = 0; kt < 8; kt++) {
            const u16* A = (kt < 4) ? s_oemb : s_oaemb;
            int kk = (kt & 3) * 32 + quad * 8;
            short8 a = *(const short8*)&A[(l15 * NA + agent) * LDC + kk];  // per-agent strided rows
            for (int n2 = 0; n2 < 2; n2++) {
                int nt = nq * 2 + n2;
                short8 b = preV[OFF_WC1 / 8 + agent * 4096 + (nt * 8 + kt) * 64 + lane];
                acc[n2] = __builtin_amdgcn_mfma_f32_16x16x32_bf16(a, b, acc[n2], 0, 0, 0);
            }
        }
        for (int n2 = 0; n2 < 2; n2++) {
            int col = (nq * 2 + n2) * 16 + l15;
            float bb = bc1[agent * HID + col];
            for (int rg = 0; rg < 4; rg++) {
                int m = quad * 4 + rg;
                s_bufB[(m * NA + agent) * LDC + col] = f2bf(leaky(acc[n2][rg] + bb));
            }
        }
    }
    __syncthreads();

    // ---- stage 5: critic layer 2 -> q_values (N padded to 16, cols 0..8 valid), f32 out ----
    for (int sj = wave; sj < NA; sj += 4) {
        int agent = sj;
        floatx4 acc = {};
        for (int kt = 0; kt < 4; kt++) {
            short8 a = *(const short8*)&s_bufB[(l15 * NA + agent) * LDC + kt * 32 + quad * 8];
            short8 b = preV[OFF_WC2 / 8 + agent * 256 + kt * 64 + lane];
            acc = __builtin_amdgcn_mfma_f32_16x16x32_bf16(a, b, acc, 0, 0, 0);
        }
        int col = l15;
        if (col < ACTD) {
            float bb = bc2[agent * ACTD + col];
            for (int rg = 0; rg < 4; rg++) {
                int m = quad * 4 + rg;
                out[((b0 + m) * NA + agent) * ACTD + col] = acc[rg] + bb;
            }
        }
    }
}

extern "C" void kernel_launch(void* const* d_in, const int* in_sizes, int n_in,
                              void* d_out, int out_size, void* d_ws, size_t ws_size,
                              hipStream_t stream) {
    const float* obs = (const float*)d_in[0];
    const float* act = (const float*)d_in[1];
    const float* Wo  = (const float*)d_in[2];
    const float* bo  = (const float*)d_in[3];
    const float* Woa = (const float*)d_in[4];
    const float* boa = (const float*)d_in[5];
    const float* Wq  = (const float*)d_in[6];
    const float* bq  = (const float*)d_in[7];
    const float* Wk  = (const float*)d_in[8];
    const float* bk  = (const float*)d_in[9];
    const float* Wv  = (const float*)d_in[10];
    const float* bv  = (const float*)d_in[11];
    const float* Wc1 = (const float*)d_in[12];
    const float* bc1 = (const float*)d_in[13];
    const float* Wc2 = (const float*)d_in[14];
    const float* bc2 = (const float*)d_in[15];
    u16* pre = (u16*)d_ws;   // needs 380928 B of workspace

    prepack_kernel<<<(PRE_TOTAL + 255) / 256, 256, 0, stream>>>(Wo, Woa, Wq, Wk, Wv, Wc1, Wc2, pre);
    fused_kernel<<<BATCH / MB, 256, 0, stream>>>(obs, act, bo, boa, bq, bk, bv, bc1, bc2, pre,
                                                 (float*)d_out);
}

// Round 3
// 290.681 us; speedup vs baseline: 1.3227x; 1.3227x over previous
//
#include <hip/hip_runtime.h>
#include <stdint.h>

typedef unsigned short u16;
typedef unsigned int u32;
typedef __attribute__((ext_vector_type(8))) short short8;
typedef __attribute__((ext_vector_type(4))) float floatx4;

#define BATCH   131072
#define NA      3
#define OBS     30
#define ACTD    9
#define HID     128
#define HEADS   4
#define HD      32
#define MB      16
#define ROWS    (MB*NA)     // 48
#define LDC     136         // padded row stride
#define LDOA    72          // oa input tile stride
#define QSCALE  0.17677669529663687f

// prepacked-weight offsets in d_ws, u16 units (fragment = 64 lanes x 8 bf16)
#define OFF_WO    0
#define OFF_WOA   12288
#define OFF_WQ    36864
#define OFF_WK    53248
#define OFF_WV    69632
#define OFF_WC1   86016
#define OFF_WC2   184320
#define PRE_TOTAL 190464

__device__ __forceinline__ u16 f2bf(float f) {          // round-nearest (ties up) — 2 VALU
    union { float f; u32 u; } v; v.f = f;
    return (u16)((v.u + 0x8000u) >> 16);
}
__device__ __forceinline__ u32 pk_bf16(float a, float b) {  // pack 2 bf16 into u32
    union { float f; u32 u; } x, y; x.f = a; y.f = b;
    return ((x.u + 0x8000u) >> 16) | ((y.u + 0x8000u) & 0xffff0000u);
}
__device__ __forceinline__ float lo16f(u32 w) { union { u32 u; float f; } v; v.u = w << 16; return v.f; }
__device__ __forceinline__ float hi16f(u32 w) { union { u32 u; float f; } v; v.u = w & 0xffff0000u; return v.f; }
__device__ __forceinline__ float leaky(float x) { return x >= 0.f ? x : 0.01f * x; }

// ------------- weight prepack: f32 [k][n] -> bf16 MFMA B-fragment order -------------
__global__ void prepack_kernel(const float* __restrict__ Wo,  const float* __restrict__ Woa,
                               const float* __restrict__ Wq,  const float* __restrict__ Wk,
                               const float* __restrict__ Wv,  const float* __restrict__ Wc1,
                               const float* __restrict__ Wc2, u16* __restrict__ out) {
    int i = blockIdx.x * blockDim.x + threadIdx.x;
    if (i >= PRE_TOTAL) return;
    const float* src; int K, KT, perA, base, Nsrc, Nlim; float scl = 1.f;
    if (i < OFF_WOA)      { src = Wo;  K = 30;  KT = 1; perA = 4096;  base = OFF_WO;  Nsrc = 128; Nlim = 128; }
    else if (i < OFF_WQ)  { src = Woa; K = 39;  KT = 2; perA = 8192;  base = OFF_WOA; Nsrc = 128; Nlim = 128; }
    else if (i < OFF_WK)  { src = Wq;  K = 128; KT = 4; perA = 16384; base = OFF_WQ;  Nsrc = 128; Nlim = 128; scl = QSCALE; }
    else if (i < OFF_WV)  { src = Wk;  K = 128; KT = 4; perA = 16384; base = OFF_WK;  Nsrc = 128; Nlim = 128; }
    else if (i < OFF_WC1) { src = Wv;  K = 128; KT = 4; perA = 16384; base = OFF_WV;  Nsrc = 128; Nlim = 128; }
    else if (i < OFF_WC2) { src = Wc1; K = 256; KT = 8; perA = 32768; base = OFF_WC1; Nsrc = 128; Nlim = 128; }
    else                  { src = Wc2; K = 128; KT = 4; perA = 2048;  base = OFF_WC2; Nsrc = 9;   Nlim = 9;   }
    int j = i - base;
    int agent = j / perA;
    int r = j - agent * perA;
    int e = r & 7, lane = (r >> 3) & 63, fk = r >> 9;
    int kt = fk % KT, nt = fk / KT;
    int n = nt * 16 + (lane & 15);
    int k = kt * 32 + (lane >> 4) * 8 + e;
    u16 v = 0;
    if (k < K && n < Nlim) v = f2bf(src[(agent * K + k) * Nsrc + n] * scl);
    out[i] = v;
}

// ---------------- fused forward ----------------
__global__ __launch_bounds__(256, 3) void fused_kernel(
    const float* __restrict__ obs, const float* __restrict__ act,
    const float* __restrict__ b_o, const float* __restrict__ b_oa,
    const float* __restrict__ bq,  const float* __restrict__ bk_, const float* __restrict__ bv,
    const float* __restrict__ bc1, const float* __restrict__ bc2,
    const u16* __restrict__ pre, float* __restrict__ out)
{
    __shared__ __align__(16) u16 s_mem[4 * ROWS * LDC];        // 52224 B
    __shared__ float2 s_probs[MB * HEADS * NA];                // 1536 B  (total 53760 -> 3 blk/CU)
    u16* s_oemb  = s_mem;                    // o_emb (persistent)
    u16* s_oaemb = s_mem + ROWS * LDC;       // oa_emb -> attn_out
    u16* s_bufA  = s_mem + 2 * ROWS * LDC;   // oa-tile -> Q -> V
    u16* s_bufB  = s_mem + 3 * ROWS * LDC;   // K -> h

    const int tid  = threadIdx.x;
    const int wave = tid >> 6, lane = tid & 63;
    const int l15  = lane & 15, quad = lane >> 4;
    const int b0   = blockIdx.x * MB;
    const short8* preV = (const short8*)pre;

    // ---- stage 0: stage [obs|act|0] tile as packed u32 writes, layout [agent][MB][LDOA] ----
    for (int g = tid; g < ROWS * 15; g += 256) {               // obs k=0..29
        int r = g / 15, s = g - r * 15;
        int n = r / MB, bl = r - n * MB;
        const float* src = &obs[((b0 + bl) * NA + n) * OBS + 2 * s];
        *(u32*)&s_bufA[n * (MB * LDOA) + bl * LDOA + 2 * s] = pk_bf16(src[0], src[1]);
    }
    for (int g = tid; g < ROWS * 5; g += 256) {                // act k=30..38, zero k=39
        int r = g / 5, s = g - r * 5;
        int n = r / MB, bl = r - n * MB;
        const float* src = &act[((b0 + bl) * NA + n) * ACTD + 2 * s];
        float v0 = src[0], v1 = (s < 4) ? src[1] : 0.f;
        *(u32*)&s_bufA[n * (MB * LDOA) + bl * LDOA + 30 + 2 * s] = pk_bf16(v0, v1);
    }
    for (int g = tid; g < ROWS * 12; g += 256) {               // zero k=40..63
        int r = g / 12, s = g - r * 12;
        int n = r / MB, bl = r - n * MB;
        *(u32*)&s_bufA[n * (MB * LDOA) + bl * LDOA + 40 + 2 * s] = 0;
    }
    __syncthreads();

    // ---- stage 1: per-agent embeds ----
    for (int sj = wave; sj < 12; sj += 4) {
        int osel = sj / 6;              // 0: o_emb  1: oa_emb
        int rem = sj % 6, agent = rem >> 1, nh = rem & 1;
        int KTn = osel ? 2 : 1;
        const float* bias = osel ? b_oa : b_o;
        int preBase = osel ? (OFF_WOA / 8 + agent * 1024) : (OFF_WO / 8 + agent * 512);
        floatx4 acc[4] = {};
        for (int kt = 0; kt < KTn; kt++) {
            short8 a = *(const short8*)&s_bufA[agent * (MB * LDOA) + l15 * LDOA + kt * 32 + quad * 8];
            for (int n4 = 0; n4 < 4; n4++) {
                int nt = nh * 4 + n4;
                short8 b = preV[preBase + (nt * KTn + kt) * 64 + lane];
                acc[n4] = __builtin_amdgcn_mfma_f32_16x16x32_bf16(a, b, acc[n4], 0, 0, 0);
            }
        }
        u16* dst = osel ? s_oaemb : s_oemb;
        for (int n4 = 0; n4 < 4; n4++) {
            int col = (nh * 4 + n4) * 16 + l15;
            float bb = bias[agent * HID + col];
            for (int rg = 0; rg < 4; rg++) {
                int m = quad * 4 + rg;
                dst[(m * NA + agent) * LDC + col] = f2bf(leaky(acc[n4][rg] + bb));
            }
        }
    }
    __syncthreads();

    // ---- stage 2: Q (scale folded into Wq/bq) and K ----
    for (int sj = wave; sj < 12; sj += 4) {
        int proj = sj / 6;              // 0: Q  1: K
        int rem = sj % 6, mt = rem >> 1, nh = rem & 1;
        const u16* A = proj ? s_oaemb : s_oemb;
        int preBase = (proj ? OFF_WK : OFF_WQ) / 8;
        const float* bias = proj ? bk_ : bq;
        float bscl = proj ? 1.f : QSCALE;
        floatx4 acc[4] = {};
        for (int kt = 0; kt < 4; kt++) {
            short8 a = *(const short8*)&A[(mt * 16 + l15) * LDC + kt * 32 + quad * 8];
            for (int n4 = 0; n4 < 4; n4++) {
                int nt = nh * 4 + n4;
                short8 b = preV[preBase + (nt * 4 + kt) * 64 + lane];
                acc[n4] = __builtin_amdgcn_mfma_f32_16x16x32_bf16(a, b, acc[n4], 0, 0, 0);
            }
        }
        u16* dst = proj ? s_bufB : s_bufA;
        for (int n4 = 0; n4 < 4; n4++) {
            int col = (nh * 4 + n4) * 16 + l15;
            float bb = bias[col] * bscl;
            for (int rg = 0; rg < 4; rg++) {
                int m = mt * 16 + quad * 4 + rg;
                dst[m * LDC + col] = f2bf(acc[n4][rg] + bb);
            }
        }
    }
    __syncthreads();

    // ---- stage 3a: masked softmax, off-diagonal only (diag term is exactly 0) ----
    if (tid < MB * HEADS * NA) {
        int e = tid / (HEADS * NA), r = tid - e * HEADS * NA, h = r / NA, n = r - h * NA;
        int m0 = (n == 0) ? 1 : 0;
        int m1 = (n == 2) ? 1 : 2;
        const uint4* qp = (const uint4*)&s_bufA[(e * NA + n) * LDC + h * HD];
        const uint4* kp0 = (const uint4*)&s_bufB[(e * NA + m0) * LDC + h * HD];
        const uint4* kp1 = (const uint4*)&s_bufB[(e * NA + m1) * LDC + h * HD];
        float s0 = 0.f, s1 = 0.f;
        for (int c = 0; c < 4; c++) {
            uint4 qw = qp[c], aw = kp0[c], bw = kp1[c];
            u32 qv[4] = {qw.x, qw.y, qw.z, qw.w};
            u32 av[4] = {aw.x, aw.y, aw.z, aw.w};
            u32 bv_[4] = {bw.x, bw.y, bw.z, bw.w};
            for (int j = 0; j < 4; j++) {
                float ql = lo16f(qv[j]), qh = hi16f(qv[j]);
                s0 += ql * lo16f(av[j]) + qh * hi16f(av[j]);
                s1 += ql * lo16f(bv_[j]) + qh * hi16f(bv_[j]);
            }
        }
        float mx = fmaxf(s0, s1);
        float p0 = __expf(s0 - mx), p1 = __expf(s1 - mx);
        float inv = 1.f / (p0 + p1);
        s_probs[(e * HEADS + h) * NA + n] = make_float2(p0 * inv, p1 * inv);
    }
    __syncthreads();

    // ---- stage 3b: V = oa_emb @ Wv + bv (12 balanced jobs) ----
    for (int sj = wave; sj < 12; sj += 4) {
        int mt = sj >> 2, np = sj & 3;
        floatx4 acc[2] = {};
        for (int kt = 0; kt < 4; kt++) {
            short8 a = *(const short8*)&s_oaemb[(mt * 16 + l15) * LDC + kt * 32 + quad * 8];
            for (int n2 = 0; n2 < 2; n2++) {
                int nt = np * 2 + n2;
                short8 b = preV[OFF_WV / 8 + (nt * 4 + kt) * 64 + lane];
                acc[n2] = __builtin_amdgcn_mfma_f32_16x16x32_bf16(a, b, acc[n2], 0, 0, 0);
            }
        }
        for (int n2 = 0; n2 < 2; n2++) {
            int col = (np * 2 + n2) * 16 + l15;
            float bb = bv[col];
            for (int rg = 0; rg < 4; rg++) {
                int m = mt * 16 + quad * 4 + rg;
                s_bufA[m * LDC + col] = f2bf(acc[n2][rg] + bb);
            }
        }
    }
    __syncthreads();

    // ---- stage 3c: attn_out = probs @ V (2 off-diagonal terms), packed b128 I/O ----
    if (tid < MB * HEADS * NA) {
        int e = tid / (HEADS * NA), r = tid - e * HEADS * NA, h = r / NA, n = r - h * NA;
        int m0 = (n == 0) ? 1 : 0;
        int m1 = (n == 2) ? 1 : 2;
        float2 p = s_probs[(e * HEADS + h) * NA + n];
        const uint4* v0p = (const uint4*)&s_bufA[(e * NA + m0) * LDC + h * HD];
        const uint4* v1p = (const uint4*)&s_bufA[(e * NA + m1) * LDC + h * HD];
        uint4* dst = (uint4*)&s_oaemb[(e * NA + n) * LDC + h * HD];
        for (int c = 0; c < 4; c++) {
            uint4 aw = v0p[c], bw = v1p[c], ow;
            u32 av[4] = {aw.x, aw.y, aw.z, aw.w};
            u32 bv_[4] = {bw.x, bw.y, bw.z, bw.w};
            u32 ov[4];
            for (int j = 0; j < 4; j++) {
                float lo = p.x * lo16f(av[j]) + p.y * lo16f(bv_[j]);
                float hi = p.x * hi16f(av[j]) + p.y * hi16f(bv_[j]);
                ov[j] = pk_bf16(lo, hi);
            }
            ow.x = ov[0]; ow.y = ov[1]; ow.z = ov[2]; ow.w = ov[3];
            dst[c] = ow;
        }
    }
    __syncthreads();

    // ---- stage 4: critic layer 1, K-split concat ----
    for (int sj = wave; sj < 12; sj += 4) {
        int agent = sj >> 2, nq = sj & 3;
        floatx4 acc[2] = {};
        for (int kt = 0; kt < 8; kt++) {
            const u16* A = (kt < 4) ? s_oemb : s_oaemb;
            int kk = (kt & 3) * 32 + quad * 8;
            short8 a = *(const short8*)&A[(l15 * NA + agent) * LDC + kk];
            for (int n2 = 0; n2 < 2; n2++) {
                int nt = nq * 2 + n2;
                short8 b = preV[OFF_WC1 / 8 + agent * 4096 + (nt * 8 + kt) * 64 + lane];
                acc[n2] = __builtin_amdgcn_mfma_f32_16x16x32_bf16(a, b, acc[n2], 0, 0, 0);
            }
        }
        for (int n2 = 0; n2 < 2; n2++) {
            int col = (nq * 2 + n2) * 16 + l15;
            float bb = bc1[agent * HID + col];
            for (int rg = 0; rg < 4; rg++) {
                int m = quad * 4 + rg;
                s_bufB[(m * NA + agent) * LDC + col] = f2bf(leaky(acc[n2][rg] + bb));
            }
        }
    }
    __syncthreads();

    // ---- stage 5: critic layer 2 -> q_values, f32 out ----
    for (int sj = wave; sj < NA; sj += 4) {
        int agent = sj;
        floatx4 acc = {};
        for (int kt = 0; kt < 4; kt++) {
            short8 a = *(const short8*)&s_bufB[(l15 * NA + agent) * LDC + kt * 32 + quad * 8];
            short8 b = preV[OFF_WC2 / 8 + agent * 256 + kt * 64 + lane];
            acc = __builtin_amdgcn_mfma_f32_16x16x32_bf16(a, b, acc, 0, 0, 0);
        }
        int col = l15;
        if (col < ACTD) {
            float bb = bc2[agent * ACTD + col];
            for (int rg = 0; rg < 4; rg++) {
                int m = quad * 4 + rg;
                out[((b0 + m) * NA + agent) * ACTD + col] = acc[rg] + bb;
            }
        }
    }
}

extern "C" void kernel_launch(void* const* d_in, const int* in_sizes, int n_in,
                              void* d_out, int out_size, void* d_ws, size_t ws_size,
                              hipStream_t stream) {
    const float* obs = (const float*)d_in[0];
    const float* act = (const float*)d_in[1];
    const float* Wo  = (const float*)d_in[2];
    const float* bo  = (const float*)d_in[3];
    const float* Woa = (const float*)d_in[4];
    const float* boa = (const float*)d_in[5];
    const float* Wq  = (const float*)d_in[6];
    const float* bq  = (const float*)d_in[7];
    const float* Wk  = (const float*)d_in[8];
    const float* bk  = (const float*)d_in[9];
    const float* Wv  = (const float*)d_in[10];
    const float* bv  = (const float*)d_in[11];
    const float* Wc1 = (const float*)d_in[12];
    const float* bc1 = (const float*)d_in[13];
    const float* Wc2 = (const float*)d_in[14];
    const float* bc2 = (const float*)d_in[15];
    u16* pre = (u16*)d_ws;   // needs 380928 B of workspace

    prepack_kernel<<<(PRE_TOTAL + 255) / 256, 256, 0, stream>>>(Wo, Woa, Wq, Wk, Wv, Wc1, Wc2, pre);
    fused_kernel<<<BATCH / MB, 256, 0, stream>>>(obs, act, bo, boa, bq, bk, bv, bc1, bc2, pre,
                                                 (float*)d_out);
}